// Round 4
// baseline (2636.258 us; speedup 1.0000x reference)
//
#include <hip/hip_runtime.h>
#include <hip/hip_bf16.h>

// Problem constants (fixed by the reference)
#define N_B   4
#define T_S   2048
#define DM    1024
#define HEADS 16
#define DK    64

// Per-batch bf16 intermediates: Qh/Kh/Vh/Aw each HEADS*T_S*DK = 2M elems
// (4 MiB) -> 16 MiB total, reused across the 4 batch iterations.
#define HB_ELEMS ((size_t)HEADS * T_S * DK)   // 2,097,152

typedef unsigned short ubf16;  // raw bf16 bits

__device__ __forceinline__ float bf2f(unsigned short u) {
    return __uint_as_float(((unsigned)u) << 16);
}
__device__ __forceinline__ unsigned short f2bf(float f) {
    unsigned u = __float_as_uint(f);
    u += 0x7fff + ((u >> 16) & 1);   // round-to-nearest-even
    return (unsigned short)(u >> 16);
}

// ---------------------------------------------------------------------------
// GEMM: Y = X[2048,1024] @ W[1024,1024] + bias, one batch.  Tile 64x64,
// BK=32, 256 threads, 4x4 fp32 acc/thread.  LDS fp32; A staged transposed.
// W and bias are fp32 (harness passes reference dtypes = float32).
// MODE 1: X fp32, Y bf16 per-batch heads [h][t][d]   (projections)
// MODE 0: X bf16 (Aw), Y fp32 row-major [2048][1024] (output projection)
// ---------------------------------------------------------------------------
template <int MODE>
__global__ __launch_bounds__(256) void gemm64(
    const void* __restrict__ Xv, const float* __restrict__ W,
    const float* __restrict__ bias, void* __restrict__ Yv)
{
    __shared__ float As[32][68];  // [k][m] transposed; 68*4B=272B row, 16B-aligned
    __shared__ float Bs[32][68];  // [k][n]

    const float* Xf = (const float*)Xv;
    const ubf16* Xb = (const ubf16*)Xv;
    float* Yf = (float*)Yv;
    ubf16* Yb = (ubf16*)Yv;

    const int tid = threadIdx.x;
    const int ty = tid >> 4, tx = tid & 15;
    const int mb = blockIdx.x * 64, nb = blockIdx.y * 64;

    float acc[4][4] = {};

    const int ar = tid >> 2;          // 0..63 (m within tile)
    const int akc = (tid & 3) * 8;    // k chunk: 0,8,16,24
    const int bk = tid >> 3;          // 0..31 (k)
    const int bc = (tid & 7) * 8;     // n chunk

    for (int kb = 0; kb < 1024; kb += 32) {
        float a8[8];
        if (MODE == 1) {
            const float* p = Xf + (size_t)(mb + ar) * 1024 + kb + akc;
            float4 a0 = *(const float4*)p;
            float4 a1 = *(const float4*)(p + 4);
            a8[0]=a0.x; a8[1]=a0.y; a8[2]=a0.z; a8[3]=a0.w;
            a8[4]=a1.x; a8[5]=a1.y; a8[6]=a1.z; a8[7]=a1.w;
        } else {
            union { uint4 v; ubf16 s[8]; } a;
            a.v = *(const uint4*)(Xb + (size_t)(mb + ar) * 1024 + kb + akc);
#pragma unroll
            for (int t = 0; t < 8; ++t) a8[t] = bf2f(a.s[t]);
        }
        const float* wp = W + (size_t)(kb + bk) * 1024 + nb + bc;
        float4 b0 = *(const float4*)wp;
        float4 b1 = *(const float4*)(wp + 4);

        __syncthreads();  // protect previous iteration's compute reads
#pragma unroll
        for (int t = 0; t < 8; ++t) As[akc + t][ar] = a8[t];  // transpose
        *(float4*)(&Bs[bk][bc])     = b0;
        *(float4*)(&Bs[bk][bc + 4]) = b1;
        __syncthreads();

#pragma unroll 8
        for (int k = 0; k < 32; ++k) {
            float4 a4 = *(const float4*)(&As[k][ty * 4]);
            float4 b4 = *(const float4*)(&Bs[k][tx * 4]);
            float af[4] = {a4.x, a4.y, a4.z, a4.w};
            float bf[4] = {b4.x, b4.y, b4.z, b4.w};
#pragma unroll
            for (int i = 0; i < 4; ++i)
#pragma unroll
                for (int j = 0; j < 4; ++j) acc[i][j] += af[i] * bf[j];
        }
    }

    float bv[4];
#pragma unroll
    for (int j = 0; j < 4; ++j) bv[j] = bias[nb + tx * 4 + j];

#pragma unroll
    for (int i = 0; i < 4; ++i) {
        const int m = mb + ty * 4 + i;   // row within batch, 0..2047
        float r0 = acc[i][0] + bv[0];
        float r1 = acc[i][1] + bv[1];
        float r2 = acc[i][2] + bv[2];
        float r3 = acc[i][3] + bv[3];
        if (MODE == 0) {
            float4 o = make_float4(r0, r1, r2, r3);
            *(float4*)(Yf + (size_t)m * 1024 + nb + tx * 4) = o;
        } else {
            const int c = nb + tx * 4;
            const int h = c >> 6, d = c & 63;          // DK=64
            ushort4 o;
            o.x = f2bf(r0); o.y = f2bf(r1); o.z = f2bf(r2); o.w = f2bf(r3);
            *(ushort4*)(Yb + ((size_t)h * T_S + m) * DK + d) = o;
        }
    }
}

// ---------------------------------------------------------------------------
// Fused attention, flash-style, one batch (bf16 in/out workspace; unchanged).
// ---------------------------------------------------------------------------
__global__ __launch_bounds__(256) void attn_kernel(
    const ubf16* __restrict__ Qh, const ubf16* __restrict__ Kh,
    const ubf16* __restrict__ Vh, const int* __restrict__ pm,
    ubf16* __restrict__ A)
{
    __shared__ ubf16 Qs[64][68];  // [k][r] transposed
    __shared__ ubf16 Ks[64][68];  // [k][c] transposed
    __shared__ ubf16 Vs[64][68];  // [c][d] row-major
    __shared__ float Ps[64][68];  // [r][c]
    __shared__ int pads[64];

    const int tid = threadIdx.x;
    const int ty = tid >> 4, tx = tid & 15;
    const int qt = blockIdx.x;    // 0..31
    const int h  = blockIdx.y;    // 0..15
    const int qb = qt * 64;
    const size_t base = (size_t)h * T_S * DK;

    const int sr = tid >> 2;            // staging row 0..63
    const int skc = (tid & 3) * 16;     // staging col chunk 0,16,32,48

    // stage Q tile (transposed)
    {
        union { uint4 v; ubf16 s[8]; } u0, u1;
        const size_t off = base + (size_t)(qb + sr) * DK + skc;
        u0.v = *(const uint4*)(Qh + off);
        u1.v = *(const uint4*)(Qh + off + 8);
#pragma unroll
        for (int t = 0; t < 8; ++t) Qs[skc + t][sr] = u0.s[t];
#pragma unroll
        for (int t = 0; t < 8; ++t) Qs[skc + 8 + t][sr] = u1.s[t];
    }

    float o[4][4] = {};
    float m_i[4], l_i[4];
#pragma unroll
    for (int i = 0; i < 4; ++i) { m_i[i] = -1.0e30f; l_i[i] = 0.f; }

    const int r0 = ty * 4, c0 = tx * 4;

    for (int kt = 0; kt <= qt; ++kt) {
        // ---- stage K (transposed), V (row-major), pad mask ----
        {
            union { uint4 v; ubf16 s[8]; } uk0, uk1, uv0, uv1;
            const size_t off = base + (size_t)(kt * 64 + sr) * DK + skc;
            uk0.v = *(const uint4*)(Kh + off);
            uk1.v = *(const uint4*)(Kh + off + 8);
            uv0.v = *(const uint4*)(Vh + off);
            uv1.v = *(const uint4*)(Vh + off + 8);
            __syncthreads();  // protect previous tile's compute reads
#pragma unroll
            for (int t = 0; t < 8; ++t) Ks[skc + t][sr] = uk0.s[t];
#pragma unroll
            for (int t = 0; t < 8; ++t) Ks[skc + 8 + t][sr] = uk1.s[t];
            *(uint2*)(&Vs[sr][skc])      = make_uint2(uv0.v.x, uv0.v.y);
            *(uint2*)(&Vs[sr][skc + 4])  = make_uint2(uv0.v.z, uv0.v.w);
            *(uint2*)(&Vs[sr][skc + 8])  = make_uint2(uv1.v.x, uv1.v.y);
            *(uint2*)(&Vs[sr][skc + 12]) = make_uint2(uv1.v.z, uv1.v.w);
            if (tid < 64) pads[tid] = pm[kt * 64 + tid];
            __syncthreads();
        }

        // ---- S = Q K^T ----
        float s[4][4] = {};
#pragma unroll 8
        for (int kk = 0; kk < 64; ++kk) {
            ushort4 qa = *(const ushort4*)(&Qs[kk][r0]);
            ushort4 ka = *(const ushort4*)(&Ks[kk][c0]);
            float qf[4] = {bf2f(qa.x), bf2f(qa.y), bf2f(qa.z), bf2f(qa.w)};
            float kf[4] = {bf2f(ka.x), bf2f(ka.y), bf2f(ka.z), bf2f(ka.w)};
#pragma unroll
            for (int i = 0; i < 4; ++i)
#pragma unroll
                for (int j = 0; j < 4; ++j) s[i][j] += qf[i] * kf[j];
        }

        // ---- online softmax (per row; reduce across the 16 tx lanes) ----
        const bool diag = (kt == qt);
#pragma unroll
        for (int i = 0; i < 4; ++i) {
            const int gq = qb + r0 + i;
            float rmax = -1.0e30f;
#pragma unroll
            for (int j = 0; j < 4; ++j) {
                float sv = s[i][j] * 0.125f;  // 1/sqrt(64)
                const int c = c0 + j;
                if (pads[c] == 0 || (diag && (kt * 64 + c) > gq)) sv = -1.0e30f;
                s[i][j] = sv;
                rmax = fmaxf(rmax, sv);
            }
#pragma unroll
            for (int off = 1; off < 16; off <<= 1)
                rmax = fmaxf(rmax, __shfl_xor(rmax, off));
            const float mnew = fmaxf(m_i[i], rmax);
            const float alpha = __expf(m_i[i] - mnew);
            float p[4], rsum = 0.f;
#pragma unroll
            for (int j = 0; j < 4; ++j) {
                p[j] = __expf(s[i][j] - mnew);
                rsum += p[j];
            }
#pragma unroll
            for (int off = 1; off < 16; off <<= 1)
                rsum += __shfl_xor(rsum, off);
            l_i[i] = l_i[i] * alpha + rsum;
            m_i[i] = mnew;
#pragma unroll
            for (int j = 0; j < 4; ++j) {
                o[i][j] *= alpha;
                Ps[r0 + i][c0 + j] = p[j];
            }
        }
        __syncthreads();

        // ---- O += P @ V ----
#pragma unroll 2
        for (int cc = 0; cc < 64; cc += 4) {
            float4 p4[4];
#pragma unroll
            for (int i = 0; i < 4; ++i) p4[i] = *(const float4*)(&Ps[r0 + i][cc]);
#pragma unroll
            for (int t = 0; t < 4; ++t) {
                ushort4 vv = *(const ushort4*)(&Vs[cc + t][c0]);
                float vf[4] = {bf2f(vv.x), bf2f(vv.y), bf2f(vv.z), bf2f(vv.w)};
#pragma unroll
                for (int i = 0; i < 4; ++i) {
                    const float pt = (&p4[i].x)[t];
#pragma unroll
                    for (int j = 0; j < 4; ++j) o[i][j] += pt * vf[j];
                }
            }
        }
    }

    // ---- epilogue: normalize, store to A[t][h*64+d] (per-batch, bf16) ----
#pragma unroll
    for (int i = 0; i < 4; ++i) {
        const float inv = 1.0f / l_i[i];
        const int gq = qb + r0 + i;
        ushort4 ov;
        ov.x = f2bf(o[i][0] * inv);
        ov.y = f2bf(o[i][1] * inv);
        ov.z = f2bf(o[i][2] * inv);
        ov.w = f2bf(o[i][3] * inv);
        *(ushort4*)(A + (size_t)gq * DM + h * DK + c0) = ov;
    }
}

// ---------------------------------------------------------------------------
extern "C" void kernel_launch(void* const* d_in, const int* in_sizes, int n_in,
                              void* d_out, int out_size, void* d_ws, size_t ws_size,
                              hipStream_t stream)
{
    // Reference dtypes: float32 everywhere except pad_mask (int32).
    const float* q  = (const float*)d_in[0];
    const float* k  = (const float*)d_in[1];
    const float* v  = (const float*)d_in[2];
    const int*   pm = (const int*)d_in[3];
    const float* Wq = (const float*)d_in[4];
    const float* bq = (const float*)d_in[5];
    const float* Wk = (const float*)d_in[6];
    const float* bk = (const float*)d_in[7];
    const float* Wv = (const float*)d_in[8];
    const float* bv = (const float*)d_in[9];
    const float* Wo = (const float*)d_in[10];
    const float* bo = (const float*)d_in[11];
    float* out = (float*)d_out;

    // per-batch bf16 workspace (16 MiB): Qh, Kh, Vh [h][t][d]; Aw [t][1024]
    ubf16* Qh = (ubf16*)d_ws;
    ubf16* Kh = Qh + HB_ELEMS;
    ubf16* Vh = Kh + HB_ELEMS;
    ubf16* Aw = Vh + HB_ELEMS;

    dim3 blk(256);
    dim3 gproj(T_S / 64, DM / 64);   // 32 x 16 (one batch: 2048 rows)
    dim3 gattn(T_S / 64, HEADS);     // 32 x 16

    for (int n = 0; n < N_B; ++n) {
        const size_t xoff = (size_t)n * T_S * DM;
        gemm64<1><<<gproj, blk, 0, stream>>>(q + xoff, Wq, bq, Qh);
        gemm64<1><<<gproj, blk, 0, stream>>>(k + xoff, Wk, bk, Kh);
        gemm64<1><<<gproj, blk, 0, stream>>>(v + xoff, Wv, bv, Vh);
        attn_kernel<<<gattn, blk, 0, stream>>>(Qh, Kh, Vh, pm + n * T_S, Aw);
        gemm64<0><<<gproj, blk, 0, stream>>>(Aw, Wo, bo, out + xoff);
    }
}

// Round 5
// 561.090 us; speedup vs baseline: 4.6985x; 4.6985x over previous
//
#include <hip/hip_runtime.h>
#include <hip/hip_bf16.h>

// Problem constants (fixed by the reference)
#define N_B   4
#define T_S   2048
#define DM    1024
#define HEADS 16
#define DK    64

typedef unsigned short ubf16;  // raw bf16 bits
typedef __attribute__((ext_vector_type(8))) short short8;   // MFMA A/B frag (8 bf16)
typedef __attribute__((ext_vector_type(4))) float floatx4;  // MFMA C/D frag

__device__ __forceinline__ float bf2f(unsigned short u) {
    return __uint_as_float(((unsigned)u) << 16);
}
__device__ __forceinline__ unsigned short f2bf(float f) {
    unsigned u = __float_as_uint(f);
    u += 0x7fff + ((u >> 16) & 1);   // round-to-nearest-even
    return (unsigned short)(u >> 16);
}

// ---------------------------------------------------------------------------
// Weight transpose+convert: W fp32 [k][n] (1024x1024) -> Wt bf16 [n][k].
// Needed so GEMM B-staging is vector loads of [n][k-chunk] rows.
// ---------------------------------------------------------------------------
__global__ __launch_bounds__(256) void wtrans(
    const float* __restrict__ W, ubf16* __restrict__ Wt)
{
    __shared__ ubf16 T[64][72];
    const int tid = threadIdx.x;
    const int kb = blockIdx.x * 64, nb = blockIdx.y * 64;
    const int r = tid >> 2, cc = (tid & 3) * 16;
    const float* p = W + (size_t)(kb + r) * 1024 + nb + cc;
#pragma unroll
    for (int t = 0; t < 16; t += 4) {
        float4 x = *(const float4*)(p + t);
        T[r][cc + t + 0] = f2bf(x.x);
        T[r][cc + t + 1] = f2bf(x.y);
        T[r][cc + t + 2] = f2bf(x.z);
        T[r][cc + t + 3] = f2bf(x.w);
    }
    __syncthreads();
    ubf16 buf[16];
#pragma unroll
    for (int t = 0; t < 16; ++t) buf[t] = T[cc + t][r];   // transpose read
    ubf16* op = Wt + (size_t)(nb + r) * 1024 + kb + cc;
    *(uint4*)op       = *(uint4*)buf;
    *(uint4*)(op + 8) = *(uint4*)(buf + 8);
}

// ---------------------------------------------------------------------------
// MFMA GEMM: Y = X[M,1024] @ W[1024,1024] + bias.  Tile 128x128, BK=32,
// 256 threads = 4 waves (2x2), each wave a 64x64 C tile = 4x4 MFMA blocks.
// Wt is bf16 [n][k] (pre-transposed).  X is fp32 (XBF=false) or bf16 (true).
// Fragment layouts (mfma_f32_16x16x32_bf16, m89-verified):
//   A: m=lane&15, k=quad*8+j  -> As[m][k] row-major, ds_read_b128
//   B: n=lane&15, k=quad*8+j  -> Bs[n][k] row-major, ds_read_b128
//   C: col=lane&15, row=quad*4+reg
// EPI: 0 = bf16 heads [n][h][t][d]; 1 = bf16 V-transposed [n][h][d][t];
//      2 = fp32 row-major [m][1024].
// ---------------------------------------------------------------------------
template <int EPI, bool XBF>
__global__ __launch_bounds__(256) void gemm_mfma(
    const void* __restrict__ Xv, const ubf16* __restrict__ Wt,
    const float* __restrict__ bias, void* __restrict__ Yv)
{
    __shared__ ubf16 As[128][40];  // [m][k], row 80B (16B-aligned)
    __shared__ ubf16 Bs[128][40];  // [n][k]

    const int tid = threadIdx.x;
    const int mb = blockIdx.x * 128, nb = blockIdx.y * 128;
    const int w = tid >> 6, lid = tid & 63, quad = lid >> 4, l15 = lid & 15;
    const int wr = (w >> 1) * 64, wc = (w & 1) * 64;
    const int sr = tid >> 1, skc = (tid & 1) * 16;   // staging: 128 rows x 32 k

    floatx4 acc[4][4] = {};

    for (int kb = 0; kb < 1024; kb += 32) {
        uint4 aw0, aw1;
        if (XBF) {
            const ubf16* p = (const ubf16*)Xv + (size_t)(mb + sr) * 1024 + kb + skc;
            aw0 = *(const uint4*)p;
            aw1 = *(const uint4*)(p + 8);
        } else {
            const float* p = (const float*)Xv + (size_t)(mb + sr) * 1024 + kb + skc;
            float4 x0 = *(const float4*)p,      x1 = *(const float4*)(p + 4);
            float4 x2 = *(const float4*)(p + 8), x3 = *(const float4*)(p + 12);
            ubf16 t[16] = {f2bf(x0.x), f2bf(x0.y), f2bf(x0.z), f2bf(x0.w),
                           f2bf(x1.x), f2bf(x1.y), f2bf(x1.z), f2bf(x1.w),
                           f2bf(x2.x), f2bf(x2.y), f2bf(x2.z), f2bf(x2.w),
                           f2bf(x3.x), f2bf(x3.y), f2bf(x3.z), f2bf(x3.w)};
            aw0 = *(uint4*)t;
            aw1 = *(uint4*)(t + 8);
        }
        const ubf16* wp = Wt + (size_t)(nb + sr) * 1024 + kb + skc;
        uint4 bw0 = *(const uint4*)wp, bw1 = *(const uint4*)(wp + 8);

        __syncthreads();  // protect previous iteration's fragment reads
        *(uint4*)(&As[sr][skc])     = aw0;
        *(uint4*)(&As[sr][skc + 8]) = aw1;
        *(uint4*)(&Bs[sr][skc])     = bw0;
        *(uint4*)(&Bs[sr][skc + 8]) = bw1;
        __syncthreads();

        short8 af[4], bf[4];
#pragma unroll
        for (int i = 0; i < 4; ++i)
            af[i] = *(const short8*)(&As[wr + i * 16 + l15][quad * 8]);
#pragma unroll
        for (int j = 0; j < 4; ++j)
            bf[j] = *(const short8*)(&Bs[wc + j * 16 + l15][quad * 8]);
#pragma unroll
        for (int i = 0; i < 4; ++i)
#pragma unroll
            for (int j = 0; j < 4; ++j)
                acc[i][j] = __builtin_amdgcn_mfma_f32_16x16x32_bf16(
                    af[i], bf[j], acc[i][j], 0, 0, 0);
    }

    // epilogue
#pragma unroll
    for (int j = 0; j < 4; ++j) {
        const int c = nb + wc + j * 16 + l15;
        const float bx = bias[c];
#pragma unroll
        for (int i = 0; i < 4; ++i) {
            if (EPI == 2) {
                float* Y = (float*)Yv;
#pragma unroll
                for (int r = 0; r < 4; ++r) {
                    const int m = mb + wr + i * 16 + quad * 4 + r;
                    Y[(size_t)m * DM + c] = acc[i][j][r] + bx;
                }
            } else if (EPI == 0) {
                ubf16* Y = (ubf16*)Yv;
                const int h = c >> 6, d = c & 63;
#pragma unroll
                for (int r = 0; r < 4; ++r) {
                    const int m = mb + wr + i * 16 + quad * 4 + r;
                    const int n = m >> 11, t = m & 2047;
                    Y[(((size_t)(n * HEADS + h)) * T_S + t) * DK + d] =
                        f2bf(acc[i][j][r] + bx);
                }
            } else {  // EPI 1: V transposed [n][h][d][t]
                ubf16* Y = (ubf16*)Yv;
                const int h = c >> 6, d = c & 63;
                const int m0 = mb + wr + i * 16 + quad * 4;
                const int n = m0 >> 11, t0 = m0 & 2047;
                ushort4 o;
                o.x = f2bf(acc[i][j][0] + bx);
                o.y = f2bf(acc[i][j][1] + bx);
                o.z = f2bf(acc[i][j][2] + bx);
                o.w = f2bf(acc[i][j][3] + bx);
                *(ushort4*)(Y + (((size_t)(n * HEADS + h)) * DK + d) * T_S + t0) = o;
            }
        }
    }
}

// ---------------------------------------------------------------------------
// MFMA flash attention.  Block = 256 thr = 4 waves; block handles (qt,h,n),
// wave w handles q rows [qt*64 + w*16, +16).  64-key tiles, causal skip.
// Q/K staged row-major [t][d]; V staged from the [h][d][t] workspace as
// Vs[d][key] so the PV B-operand is a b128 read.  P round-trips through
// per-wave LDS rows (C-layout -> A-layout, per guide m120).
// qt reversed so long (high-qt) blocks launch first (tail balance).
// ---------------------------------------------------------------------------
__global__ __launch_bounds__(256) void attn_mfma(
    const ubf16* __restrict__ Qh, const ubf16* __restrict__ Kh,
    const ubf16* __restrict__ Vt, const int* __restrict__ pm,
    ubf16* __restrict__ A)
{
    __shared__ ubf16 Qs[64][72];  // [q][d]
    __shared__ ubf16 Ks[64][72];  // [key][d]
    __shared__ ubf16 Vs[64][72];  // [d][key]
    __shared__ ubf16 Ps[64][72];  // [q][key], per-wave 16-row slabs
    __shared__ int pads[64];

    const int tid = threadIdx.x;
    const int w = tid >> 6, lid = tid & 63, quad = lid >> 4, l15 = lid & 15;
    const int qt = (int)gridDim.x - 1 - (int)blockIdx.x;
    const int h = blockIdx.y, n = blockIdx.z;
    const int qb = qt * 64;
    const size_t qkbase = ((size_t)(n * HEADS + h)) * T_S * DK;
    const size_t vbase  = ((size_t)(n * HEADS + h)) * DK * T_S;
    const int sr = tid >> 2, skc = (tid & 3) * 16;

    // stage Q tile (row-major)
    {
        const ubf16* p = Qh + qkbase + (size_t)(qb + sr) * DK + skc;
        *(uint4*)(&Qs[sr][skc])     = *(const uint4*)p;
        *(uint4*)(&Qs[sr][skc + 8]) = *(const uint4*)(p + 8);
    }

    floatx4 o[4] = {};
    float m_i[4], l_i[4];
#pragma unroll
    for (int r = 0; r < 4; ++r) { m_i[r] = -1.0e30f; l_i[r] = 0.f; }

    const int qrow0 = qb + w * 16 + quad * 4;

    for (int kt = 0; kt <= qt; ++kt) {
        const ubf16* kp = Kh + qkbase + (size_t)(kt * 64 + sr) * DK + skc;
        const ubf16* vp = Vt + vbase + (size_t)sr * T_S + kt * 64 + skc;
        uint4 k0 = *(const uint4*)kp, k1 = *(const uint4*)(kp + 8);
        uint4 v0 = *(const uint4*)vp, v1 = *(const uint4*)(vp + 8);
        __syncthreads();  // protect previous iteration's Ks/Vs reads
        *(uint4*)(&Ks[sr][skc])     = k0;
        *(uint4*)(&Ks[sr][skc + 8]) = k1;
        *(uint4*)(&Vs[sr][skc])     = v0;
        *(uint4*)(&Vs[sr][skc + 8]) = v1;
        if (tid < 64) pads[tid] = pm[(size_t)n * T_S + kt * 64 + tid];
        __syncthreads();

        // ---- S = Q K^T: 8 MFMAs (4 col-blocks x 2 d-chunks) ----
        short8 q0 = *(const short8*)(&Qs[w * 16 + l15][quad * 8]);
        short8 q1 = *(const short8*)(&Qs[w * 16 + l15][32 + quad * 8]);
        floatx4 s[4] = {};
#pragma unroll
        for (int cb = 0; cb < 4; ++cb) {
            short8 kf0 = *(const short8*)(&Ks[cb * 16 + l15][quad * 8]);
            short8 kf1 = *(const short8*)(&Ks[cb * 16 + l15][32 + quad * 8]);
            s[cb] = __builtin_amdgcn_mfma_f32_16x16x32_bf16(q0, kf0, s[cb], 0, 0, 0);
            s[cb] = __builtin_amdgcn_mfma_f32_16x16x32_bf16(q1, kf1, s[cb], 0, 0, 0);
        }

        // ---- online softmax (C-layout: row=quad*4+r, col=cb*16+l15) ----
        const bool diag = (kt == qt);
        bool pok[4];
#pragma unroll
        for (int cb = 0; cb < 4; ++cb) pok[cb] = (pads[cb * 16 + l15] != 0);
#pragma unroll
        for (int r = 0; r < 4; ++r) {
            const int gq = qrow0 + r;
            float vmax = -1.0e30f;
#pragma unroll
            for (int cb = 0; cb < 4; ++cb) {
                float sv = s[cb][r] * 0.125f;  // 1/sqrt(64)
                const int col = kt * 64 + cb * 16 + l15;
                if (!pok[cb] || (diag && col > gq)) sv = -1.0e30f;
                s[cb][r] = sv;
                vmax = fmaxf(vmax, sv);
            }
            vmax = fmaxf(vmax, __shfl_xor(vmax, 1));
            vmax = fmaxf(vmax, __shfl_xor(vmax, 2));
            vmax = fmaxf(vmax, __shfl_xor(vmax, 4));
            vmax = fmaxf(vmax, __shfl_xor(vmax, 8));
            const float mnew = fmaxf(m_i[r], vmax);
            const float alpha = __expf(m_i[r] - mnew);
            float rs = 0.f;
#pragma unroll
            for (int cb = 0; cb < 4; ++cb) {
                const float pv = __expf(s[cb][r] - mnew);
                s[cb][r] = pv;
                rs += pv;
            }
            rs += __shfl_xor(rs, 1);
            rs += __shfl_xor(rs, 2);
            rs += __shfl_xor(rs, 4);
            rs += __shfl_xor(rs, 8);
            l_i[r] = l_i[r] * alpha + rs;
            m_i[r] = mnew;
#pragma unroll
            for (int db = 0; db < 4; ++db) o[db][r] *= alpha;
#pragma unroll
            for (int cb = 0; cb < 4; ++cb)
                Ps[w * 16 + quad * 4 + r][cb * 16 + l15] = f2bf(s[cb][r]);
        }
        __syncthreads();  // Ps visibility (uniform: all waves share the kt loop)

        // ---- O += P @ V: 8 MFMAs (4 d-blocks x 2 key-chunks) ----
        short8 p0 = *(const short8*)(&Ps[w * 16 + l15][quad * 8]);
        short8 p1 = *(const short8*)(&Ps[w * 16 + l15][32 + quad * 8]);
#pragma unroll
        for (int db = 0; db < 4; ++db) {
            short8 vf0 = *(const short8*)(&Vs[db * 16 + l15][quad * 8]);
            short8 vf1 = *(const short8*)(&Vs[db * 16 + l15][32 + quad * 8]);
            o[db] = __builtin_amdgcn_mfma_f32_16x16x32_bf16(p0, vf0, o[db], 0, 0, 0);
            o[db] = __builtin_amdgcn_mfma_f32_16x16x32_bf16(p1, vf1, o[db], 0, 0, 0);
        }
    }

    // ---- epilogue: normalize, store bf16 to A[n][t][h*64+d] ----
#pragma unroll
    for (int r = 0; r < 4; ++r) {
        const float inv = l_i[r] > 0.f ? 1.0f / l_i[r] : 0.f;
        const int gq = qrow0 + r;
        ubf16* ap = A + ((size_t)n * T_S + gq) * DM + h * DK;
#pragma unroll
        for (int db = 0; db < 4; ++db)
            ap[db * 16 + l15] = f2bf(o[db][r] * inv);
    }
}

// ---------------------------------------------------------------------------
extern "C" void kernel_launch(void* const* d_in, const int* in_sizes, int n_in,
                              void* d_out, int out_size, void* d_ws, size_t ws_size,
                              hipStream_t stream)
{
    const float* q  = (const float*)d_in[0];
    const float* k  = (const float*)d_in[1];
    const float* v  = (const float*)d_in[2];
    const int*   pm = (const int*)d_in[3];
    const float* Wq = (const float*)d_in[4];
    const float* bq = (const float*)d_in[5];
    const float* Wk = (const float*)d_in[6];
    const float* bk = (const float*)d_in[7];
    const float* Wv = (const float*)d_in[8];
    const float* bv = (const float*)d_in[9];
    const float* Wo = (const float*)d_in[10];
    const float* bo = (const float*)d_in[11];
    float* out = (float*)d_out;

    const size_t WT_E = (size_t)1024 * 1024;      // per-weight bf16 elems (2 MiB)
    const size_t HB_E = (size_t)8192 * 1024;      // batched per-tensor elems (16 MiB)
    const size_t PB_E = (size_t)2048 * 1024;      // per-batch elems (4 MiB)

    ubf16* WtQ = (ubf16*)d_ws;
    ubf16* WtK = WtQ + WT_E;
    ubf16* WtV = WtK + WT_E;
    ubf16* WtO = WtV + WT_E;
    ubf16* base = WtO + WT_E;

    dim3 blk(256);
    dim3 gtr(16, 16);
    wtrans<<<gtr, blk, 0, stream>>>(Wq, WtQ);
    wtrans<<<gtr, blk, 0, stream>>>(Wk, WtK);
    wtrans<<<gtr, blk, 0, stream>>>(Wv, WtV);
    wtrans<<<gtr, blk, 0, stream>>>(Wo, WtO);

    const size_t need_batched = (4 * WT_E + 4 * HB_E) * sizeof(ubf16);  // 72 MiB
    if (ws_size >= need_batched) {
        ubf16* Qh = base;
        ubf16* Kh = Qh + HB_E;
        ubf16* Vt = Kh + HB_E;
        ubf16* Aw = Vt + HB_E;
        dim3 gg(64, 8);            // M=8192, N=1024, 128x128 tiles
        gemm_mfma<0, false><<<gg, blk, 0, stream>>>(q, WtQ, bq, Qh);
        gemm_mfma<0, false><<<gg, blk, 0, stream>>>(k, WtK, bk, Kh);
        gemm_mfma<1, false><<<gg, blk, 0, stream>>>(v, WtV, bv, Vt);
        dim3 ga(32, HEADS, N_B);   // 2048 blocks
        attn_mfma<<<ga, blk, 0, stream>>>(Qh, Kh, Vt, pm, Aw);
        gemm_mfma<2, true><<<gg, blk, 0, stream>>>(Aw, WtO, bo, out);
    } else {
        // per-batch fallback (24 MiB workspace)
        ubf16* Qh = base;
        ubf16* Kh = Qh + PB_E;
        ubf16* Vt = Kh + PB_E;
        ubf16* Aw = Vt + PB_E;
        dim3 gg(16, 8);
        dim3 ga(32, HEADS, 1);
        for (int n = 0; n < N_B; ++n) {
            const size_t xoff = (size_t)n * T_S * DM;
            gemm_mfma<0, false><<<gg, blk, 0, stream>>>(q + xoff, WtQ, bq, Qh);
            gemm_mfma<0, false><<<gg, blk, 0, stream>>>(k + xoff, WtK, bk, Kh);
            gemm_mfma<1, false><<<gg, blk, 0, stream>>>(v + xoff, WtV, bv, Vt);
            attn_mfma<<<ga, blk, 0, stream>>>(Qh, Kh, Vt, pm + n * T_S, Aw);
            gemm_mfma<2, true><<<gg, blk, 0, stream>>>(Aw, WtO, bo, out + xoff);
        }
    }
}

// Round 6
// 460.656 us; speedup vs baseline: 5.7228x; 1.2180x over previous
//
#include <hip/hip_runtime.h>
#include <hip/hip_bf16.h>

// Problem constants (fixed by the reference)
#define N_B   4
#define T_S   2048
#define DM    1024
#define HEADS 16
#define DK    64

typedef unsigned short ubf16;  // raw bf16 bits
typedef __attribute__((ext_vector_type(8))) short short8;   // MFMA A/B frag (8 bf16)
typedef __attribute__((ext_vector_type(4))) float floatx4;  // MFMA C/D frag

__device__ __forceinline__ float bf2f(unsigned short u) {
    return __uint_as_float(((unsigned)u) << 16);
}
__device__ __forceinline__ unsigned short f2bf(float f) {
    unsigned u = __float_as_uint(f);
    u += 0x7fff + ((u >> 16) & 1);   // round-to-nearest-even
    return (unsigned short)(u >> 16);
}

// ---------------------------------------------------------------------------
// Weight transpose+convert: W fp32 [k][n] (1024x1024) -> Wt bf16 [n][k].
// ---------------------------------------------------------------------------
__global__ __launch_bounds__(256) void wtrans(
    const float* __restrict__ W, ubf16* __restrict__ Wt)
{
    __shared__ ubf16 T[64][72];
    const int tid = threadIdx.x;
    const int kb = blockIdx.x * 64, nb = blockIdx.y * 64;
    const int r = tid >> 2, cc = (tid & 3) * 16;
    const float* p = W + (size_t)(kb + r) * 1024 + nb + cc;
#pragma unroll
    for (int t = 0; t < 16; t += 4) {
        float4 x = *(const float4*)(p + t);
        T[r][cc + t + 0] = f2bf(x.x);
        T[r][cc + t + 1] = f2bf(x.y);
        T[r][cc + t + 2] = f2bf(x.z);
        T[r][cc + t + 3] = f2bf(x.w);
    }
    __syncthreads();
    ubf16 buf[16];
#pragma unroll
    for (int t = 0; t < 16; ++t) buf[t] = T[cc + t][r];   // transpose read
    ubf16* op = Wt + (size_t)(nb + r) * 1024 + kb + cc;
    *(uint4*)op       = *(uint4*)buf;
    *(uint4*)(op + 8) = *(uint4*)(buf + 8);
}

// ---------------------------------------------------------------------------
// MFMA GEMM: Y = X[M,1024] @ W[1024,1024] + bias.  Tile 128x128, BK=32,
// 256 threads = 4 waves (2x2), each wave a 64x64 C tile = 4x4 MFMA blocks.
// Wt is bf16 [n][k] (pre-transposed).  X is fp32 (XBF=false) or bf16 (true).
// Fragment layouts (mfma_f32_16x16x32_bf16, m89-verified):
//   A: m=lane&15, k=quad*8+j  -> As[m][k] row-major, ds_read_b128
//   B: n=lane&15, k=quad*8+j  -> Bs[n][k] row-major, ds_read_b128
//   C: col=lane&15, row=quad*4+reg
// EPI: 0 = bf16 heads [n][h][t][d]; 1 = bf16 V-transposed [n][h][d][t];
//      2 = fp32 row-major [m][1024].
// ---------------------------------------------------------------------------
template <int EPI, bool XBF>
__global__ __launch_bounds__(256) void gemm_mfma(
    const void* __restrict__ Xv, const ubf16* __restrict__ Wt,
    const float* __restrict__ bias, void* __restrict__ Yv)
{
    __shared__ ubf16 As[128][40];  // [m][k], row 80B (16B-aligned)
    __shared__ ubf16 Bs[128][40];  // [n][k]

    const int tid = threadIdx.x;
    const int mb = blockIdx.x * 128, nb = blockIdx.y * 128;
    const int w = tid >> 6, lid = tid & 63, quad = lid >> 4, l15 = lid & 15;
    const int wr = (w >> 1) * 64, wc = (w & 1) * 64;
    const int sr = tid >> 1, skc = (tid & 1) * 16;   // staging: 128 rows x 32 k

    floatx4 acc[4][4] = {};

    for (int kb = 0; kb < 1024; kb += 32) {
        uint4 aw0, aw1;
        if (XBF) {
            const ubf16* p = (const ubf16*)Xv + (size_t)(mb + sr) * 1024 + kb + skc;
            aw0 = *(const uint4*)p;
            aw1 = *(const uint4*)(p + 8);
        } else {
            const float* p = (const float*)Xv + (size_t)(mb + sr) * 1024 + kb + skc;
            float4 x0 = *(const float4*)p,      x1 = *(const float4*)(p + 4);
            float4 x2 = *(const float4*)(p + 8), x3 = *(const float4*)(p + 12);
            ubf16 t[16] = {f2bf(x0.x), f2bf(x0.y), f2bf(x0.z), f2bf(x0.w),
                           f2bf(x1.x), f2bf(x1.y), f2bf(x1.z), f2bf(x1.w),
                           f2bf(x2.x), f2bf(x2.y), f2bf(x2.z), f2bf(x2.w),
                           f2bf(x3.x), f2bf(x3.y), f2bf(x3.z), f2bf(x3.w)};
            aw0 = *(uint4*)t;
            aw1 = *(uint4*)(t + 8);
        }
        const ubf16* wp = Wt + (size_t)(nb + sr) * 1024 + kb + skc;
        uint4 bw0 = *(const uint4*)wp, bw1 = *(const uint4*)(wp + 8);

        __syncthreads();  // protect previous iteration's fragment reads
        *(uint4*)(&As[sr][skc])     = aw0;
        *(uint4*)(&As[sr][skc + 8]) = aw1;
        *(uint4*)(&Bs[sr][skc])     = bw0;
        *(uint4*)(&Bs[sr][skc + 8]) = bw1;
        __syncthreads();

        short8 af[4], bf[4];
#pragma unroll
        for (int i = 0; i < 4; ++i)
            af[i] = *(const short8*)(&As[wr + i * 16 + l15][quad * 8]);
#pragma unroll
        for (int j = 0; j < 4; ++j)
            bf[j] = *(const short8*)(&Bs[wc + j * 16 + l15][quad * 8]);
#pragma unroll
        for (int i = 0; i < 4; ++i)
#pragma unroll
            for (int j = 0; j < 4; ++j)
                acc[i][j] = __builtin_amdgcn_mfma_f32_16x16x32_bf16(
                    af[i], bf[j], acc[i][j], 0, 0, 0);
    }

    // epilogue
#pragma unroll
    for (int j = 0; j < 4; ++j) {
        const int c = nb + wc + j * 16 + l15;
        const float bx = bias[c];
#pragma unroll
        for (int i = 0; i < 4; ++i) {
            if (EPI == 2) {
                float* Y = (float*)Yv;
#pragma unroll
                for (int r = 0; r < 4; ++r) {
                    const int m = mb + wr + i * 16 + quad * 4 + r;
                    Y[(size_t)m * DM + c] = acc[i][j][r] + bx;
                }
            } else if (EPI == 0) {
                ubf16* Y = (ubf16*)Yv;
                const int h = c >> 6, d = c & 63;
#pragma unroll
                for (int r = 0; r < 4; ++r) {
                    const int m = mb + wr + i * 16 + quad * 4 + r;
                    const int n = m >> 11, t = m & 2047;
                    Y[(((size_t)(n * HEADS + h)) * T_S + t) * DK + d] =
                        f2bf(acc[i][j][r] + bx);
                }
            } else {  // EPI 1: V transposed [n][h][d][t]
                ubf16* Y = (ubf16*)Yv;
                const int h = c >> 6, d = c & 63;
                const int m0 = mb + wr + i * 16 + quad * 4;
                const int n = m0 >> 11, t0 = m0 & 2047;
                ushort4 o;
                o.x = f2bf(acc[i][j][0] + bx);
                o.y = f2bf(acc[i][j][1] + bx);
                o.z = f2bf(acc[i][j][2] + bx);
                o.w = f2bf(acc[i][j][3] + bx);
                *(ushort4*)(Y + (((size_t)(n * HEADS + h)) * DK + d) * T_S + t0) = o;
            }
        }
    }
}

// ---------------------------------------------------------------------------
// MFMA flash attention, v2.
//  - No-rescale softmax: p = exp(s/8) (masked -> 0); l additive, normalized
//    once at the end.  (scores are O(1)-scale: overflow needs 88 sigma.)
//  - PV operand-swapped: O^T = MFMA(A=V^T frag, B=P frag).  P is written AND
//    read only in this wave's 16-row slab of Ps -> wave-local s_waitcnt
//    instead of a block barrier.
//  - Q fragments hoisted out of the key loop; pad mask via __ballot.
// Block = 4 waves; wave w owns q rows [qt*64+w*16, +16).  qt reversed for
// causal load balance.
// ---------------------------------------------------------------------------
__global__ __launch_bounds__(256) void attn_mfma(
    const ubf16* __restrict__ Qh, const ubf16* __restrict__ Kh,
    const ubf16* __restrict__ Vt, const int* __restrict__ pm,
    ubf16* __restrict__ A)
{
    __shared__ ubf16 Qs[64][72];  // [q][d]
    __shared__ ubf16 Ks[64][72];  // [key][d]
    __shared__ ubf16 Vs[64][72];  // [d][key]
    __shared__ ubf16 Ps[64][72];  // [q][key], per-wave 16-row slabs
    __shared__ float lbuf[4][16];

    const int tid = threadIdx.x;
    const int w = tid >> 6, lid = tid & 63, quad = lid >> 4, l15 = lid & 15;
    const int qt = (int)gridDim.x - 1 - (int)blockIdx.x;
    const int h = blockIdx.y, n = blockIdx.z;
    const int qb = qt * 64;
    const size_t qkbase = ((size_t)(n * HEADS + h)) * T_S * DK;
    const size_t vbase  = ((size_t)(n * HEADS + h)) * DK * T_S;
    const int sr = tid >> 2, skc = (tid & 3) * 16;

    // stage Q tile (row-major), then hoist this wave's Q fragments
    {
        const ubf16* p = Qh + qkbase + (size_t)(qb + sr) * DK + skc;
        *(uint4*)(&Qs[sr][skc])     = *(const uint4*)p;
        *(uint4*)(&Qs[sr][skc + 8]) = *(const uint4*)(p + 8);
    }
    __syncthreads();
    const short8 q0 = *(const short8*)(&Qs[w * 16 + l15][quad * 8]);
    const short8 q1 = *(const short8*)(&Qs[w * 16 + l15][32 + quad * 8]);

    floatx4 o[4] = {};   // O^T: d = db*16+quad*4+r, q = w*16+l15
    float lsum[4] = {};  // partial row sums, q = w*16+quad*4+r

    for (int kt = 0; kt <= qt; ++kt) {
        const ubf16* kp = Kh + qkbase + (size_t)(kt * 64 + sr) * DK + skc;
        const ubf16* vp = Vt + vbase + (size_t)sr * T_S + kt * 64 + skc;
        uint4 k0 = *(const uint4*)kp, k1 = *(const uint4*)(kp + 8);
        uint4 v0 = *(const uint4*)vp, v1 = *(const uint4*)(vp + 8);
        const int pmv = pm[(size_t)n * T_S + kt * 64 + lid];
        __syncthreads();  // protect previous iteration's Ks/Vs/Ps reads
        *(uint4*)(&Ks[sr][skc])     = k0;
        *(uint4*)(&Ks[sr][skc + 8]) = k1;
        *(uint4*)(&Vs[sr][skc])     = v0;
        *(uint4*)(&Vs[sr][skc + 8]) = v1;
        __syncthreads();

        // ---- S = Q K^T: 8 MFMAs.  C-layout: q=quad*4+r, key=cb*16+l15 ----
        floatx4 s[4] = {};
#pragma unroll
        for (int cb = 0; cb < 4; ++cb) {
            short8 kf0 = *(const short8*)(&Ks[cb * 16 + l15][quad * 8]);
            short8 kf1 = *(const short8*)(&Ks[cb * 16 + l15][32 + quad * 8]);
            s[cb] = __builtin_amdgcn_mfma_f32_16x16x32_bf16(q0, kf0, s[cb], 0, 0, 0);
            s[cb] = __builtin_amdgcn_mfma_f32_16x16x32_bf16(q1, kf1, s[cb], 0, 0, 0);
        }

        // ---- p = exp(s/8), masked -> 0; accumulate l; stash P in own slab ----
        const unsigned long long pmask = __ballot(pmv != 0);
        const bool diag = (kt == qt);
#pragma unroll
        for (int cb = 0; cb < 4; ++cb) {
            const unsigned okb = ((unsigned)(pmask >> (cb * 16)) >> l15) & 1u;
            const int col = cb * 16 + l15;   // in-tile key index
#pragma unroll
            for (int r = 0; r < 4; ++r) {
                float p = __expf(s[cb][r] * 0.125f);
                if (!okb || (diag && col > (w * 16 + quad * 4 + r))) p = 0.f;
                lsum[r] += p;
                Ps[w * 16 + quad * 4 + r][col] = f2bf(p);
            }
        }
        // wave-local visibility for own Ps slab (no block barrier needed)
        __asm__ volatile("s_waitcnt lgkmcnt(0)" ::: "memory");
        __builtin_amdgcn_wave_barrier();

        // ---- O^T += MFMA(A=V^T, B=P): 8 MFMAs ----
        short8 pf0 = *(const short8*)(&Ps[w * 16 + l15][quad * 8]);
        short8 pf1 = *(const short8*)(&Ps[w * 16 + l15][32 + quad * 8]);
#pragma unroll
        for (int db = 0; db < 4; ++db) {
            short8 vf0 = *(const short8*)(&Vs[db * 16 + l15][quad * 8]);
            short8 vf1 = *(const short8*)(&Vs[db * 16 + l15][32 + quad * 8]);
            o[db] = __builtin_amdgcn_mfma_f32_16x16x32_bf16(vf0, pf0, o[db], 0, 0, 0);
            o[db] = __builtin_amdgcn_mfma_f32_16x16x32_bf16(vf1, pf1, o[db], 0, 0, 0);
        }
    }

    // ---- final l reduction (once): sum over the 16 l15 lanes per q-row ----
#pragma unroll
    for (int r = 0; r < 4; ++r) {
        lsum[r] += __shfl_xor(lsum[r], 1);
        lsum[r] += __shfl_xor(lsum[r], 2);
        lsum[r] += __shfl_xor(lsum[r], 4);
        lsum[r] += __shfl_xor(lsum[r], 8);
    }
    if (l15 == 0) {
#pragma unroll
        for (int r = 0; r < 4; ++r) lbuf[w][quad * 4 + r] = lsum[r];
    }
    __asm__ volatile("s_waitcnt lgkmcnt(0)" ::: "memory");
    __builtin_amdgcn_wave_barrier();
    const float lq = lbuf[w][l15];
    const float inv = lq > 0.f ? 1.0f / lq : 0.f;

    // ---- store: lane owns row q = qb + w*16 + l15, d packs of 4 ----
    ubf16* ap = A + ((size_t)n * T_S + qb + w * 16 + l15) * DM + h * DK;
#pragma unroll
    for (int db = 0; db < 4; ++db) {
        ushort4 ov;
        ov.x = f2bf(o[db][0] * inv);
        ov.y = f2bf(o[db][1] * inv);
        ov.z = f2bf(o[db][2] * inv);
        ov.w = f2bf(o[db][3] * inv);
        *(ushort4*)(ap + db * 16 + quad * 4) = ov;
    }
}

// ---------------------------------------------------------------------------
extern "C" void kernel_launch(void* const* d_in, const int* in_sizes, int n_in,
                              void* d_out, int out_size, void* d_ws, size_t ws_size,
                              hipStream_t stream)
{
    const float* q  = (const float*)d_in[0];
    const float* k  = (const float*)d_in[1];
    const float* v  = (const float*)d_in[2];
    const int*   pm = (const int*)d_in[3];
    const float* Wq = (const float*)d_in[4];
    const float* bq = (const float*)d_in[5];
    const float* Wk = (const float*)d_in[6];
    const float* bk = (const float*)d_in[7];
    const float* Wv = (const float*)d_in[8];
    const float* bv = (const float*)d_in[9];
    const float* Wo = (const float*)d_in[10];
    const float* bo = (const float*)d_in[11];
    float* out = (float*)d_out;

    const size_t WT_E = (size_t)1024 * 1024;      // per-weight bf16 elems (2 MiB)
    const size_t HB_E = (size_t)8192 * 1024;      // batched per-tensor elems (16 MiB)
    const size_t PB_E = (size_t)2048 * 1024;      // per-batch elems (4 MiB)

    ubf16* WtQ = (ubf16*)d_ws;
    ubf16* WtK = WtQ + WT_E;
    ubf16* WtV = WtK + WT_E;
    ubf16* WtO = WtV + WT_E;
    ubf16* base = WtO + WT_E;

    dim3 blk(256);
    dim3 gtr(16, 16);
    wtrans<<<gtr, blk, 0, stream>>>(Wq, WtQ);
    wtrans<<<gtr, blk, 0, stream>>>(Wk, WtK);
    wtrans<<<gtr, blk, 0, stream>>>(Wv, WtV);
    wtrans<<<gtr, blk, 0, stream>>>(Wo, WtO);

    const size_t need_batched = (4 * WT_E + 4 * HB_E) * sizeof(ubf16);  // 72 MiB
    if (ws_size >= need_batched) {
        ubf16* Qh = base;
        ubf16* Kh = Qh + HB_E;
        ubf16* Vt = Kh + HB_E;
        ubf16* Aw = Vt + HB_E;
        dim3 gg(64, 8);            // M=8192, N=1024, 128x128 tiles
        gemm_mfma<0, false><<<gg, blk, 0, stream>>>(q, WtQ, bq, Qh);
        gemm_mfma<0, false><<<gg, blk, 0, stream>>>(k, WtK, bk, Kh);
        gemm_mfma<1, false><<<gg, blk, 0, stream>>>(v, WtV, bv, Vt);
        dim3 ga(32, HEADS, N_B);   // 2048 blocks
        attn_mfma<<<ga, blk, 0, stream>>>(Qh, Kh, Vt, pm, Aw);
        gemm_mfma<2, true><<<gg, blk, 0, stream>>>(Aw, WtO, bo, out);
    } else {
        // per-batch fallback (24 MiB workspace)
        ubf16* Qh = base;
        ubf16* Kh = Qh + PB_E;
        ubf16* Vt = Kh + PB_E;
        ubf16* Aw = Vt + PB_E;
        dim3 gg(16, 8);
        dim3 ga(32, HEADS, 1);
        for (int n = 0; n < N_B; ++n) {
            const size_t xoff = (size_t)n * T_S * DM;
            gemm_mfma<0, false><<<gg, blk, 0, stream>>>(q + xoff, WtQ, bq, Qh);
            gemm_mfma<0, false><<<gg, blk, 0, stream>>>(k + xoff, WtK, bk, Kh);
            gemm_mfma<1, false><<<gg, blk, 0, stream>>>(v + xoff, WtV, bv, Vt);
            attn_mfma<<<ga, blk, 0, stream>>>(Qh, Kh, Vt, pm + n * T_S, Aw);
            gemm_mfma<2, true><<<gg, blk, 0, stream>>>(Aw, WtO, bo, out + xoff);
        }
    }
}

// Round 7
// 417.600 us; speedup vs baseline: 6.3129x; 1.1031x over previous
//
#include <hip/hip_runtime.h>
#include <hip/hip_bf16.h>

// Problem constants (fixed by the reference)
#define N_B   4
#define T_S   2048
#define DM    1024
#define HEADS 16
#define DK    64

typedef unsigned short ubf16;  // raw bf16 bits
typedef __attribute__((ext_vector_type(8))) short short8;   // MFMA A/B frag (8 bf16)
typedef __attribute__((ext_vector_type(4))) float floatx4;  // MFMA C/D frag

__device__ __forceinline__ float bf2f(unsigned short u) {
    return __uint_as_float(((unsigned)u) << 16);
}
__device__ __forceinline__ unsigned short f2bf(float f) {
    unsigned u = __float_as_uint(f);
    u += 0x7fff + ((u >> 16) & 1);   // round-to-nearest-even
    return (unsigned short)(u >> 16);
}

// async global->LDS DMA, 16 B per lane; LDS dest = wave-uniform base + lane*16
__device__ __forceinline__ void async_copy16(const ubf16* g, ubf16* l) {
    __builtin_amdgcn_global_load_lds(
        (const __attribute__((address_space(1))) void*)g,
        (__attribute__((address_space(3))) void*)l, 16, 0, 0);
}

// ---------------------------------------------------------------------------
// fp32 -> bf16 bulk convert (8 elems/thread)
// ---------------------------------------------------------------------------
__global__ __launch_bounds__(256) void cvt_bf16(
    const float* __restrict__ X, ubf16* __restrict__ Y, int n8)
{
    const int i = blockIdx.x * 256 + threadIdx.x;
    if (i < n8) {
        const float4 a = ((const float4*)X)[2 * i];
        const float4 b = ((const float4*)X)[2 * i + 1];
        ushort4 o0, o1;
        o0.x = f2bf(a.x); o0.y = f2bf(a.y); o0.z = f2bf(a.z); o0.w = f2bf(a.w);
        o1.x = f2bf(b.x); o1.y = f2bf(b.y); o1.z = f2bf(b.z); o1.w = f2bf(b.w);
        ((ushort4*)Y)[2 * i]     = o0;
        ((ushort4*)Y)[2 * i + 1] = o1;
    }
}

// ---------------------------------------------------------------------------
// Weight transpose+convert: W fp32 [k][n] (1024x1024) -> Wt bf16 [n][k].
// ---------------------------------------------------------------------------
__global__ __launch_bounds__(256) void wtrans(
    const float* __restrict__ W, ubf16* __restrict__ Wt)
{
    __shared__ ubf16 T[64][72];
    const int tid = threadIdx.x;
    const int kb = blockIdx.x * 64, nb = blockIdx.y * 64;
    const int r = tid >> 2, cc = (tid & 3) * 16;
    const float* p = W + (size_t)(kb + r) * 1024 + nb + cc;
#pragma unroll
    for (int t = 0; t < 16; t += 4) {
        float4 x = *(const float4*)(p + t);
        T[r][cc + t + 0] = f2bf(x.x);
        T[r][cc + t + 1] = f2bf(x.y);
        T[r][cc + t + 2] = f2bf(x.z);
        T[r][cc + t + 3] = f2bf(x.w);
    }
    __syncthreads();
    ubf16 buf[16];
#pragma unroll
    for (int t = 0; t < 16; ++t) buf[t] = T[cc + t][r];   // transpose read
    ubf16* op = Wt + (size_t)(nb + r) * 1024 + kb + cc;
    *(uint4*)op       = *(uint4*)buf;
    *(uint4*)(op + 8) = *(uint4*)(buf + 8);
}

// ---------------------------------------------------------------------------
// MFMA GEMM: Y = X[M,1024](bf16) @ Wt^T + bias.  Tile 128x128, BK=32,
// 4 waves (2x2), 64x64 C per wave.  Staging via global_load_lds width=16:
// As/Bs are UNPADDED [128][32] (64 B rows) because the DMA writes
// wave-uniform-base + lane*16 contiguously.  Wave w stages rows
// [w*32, w*32+32) of both tiles (2 calls each).  Fragment reads are
// ds_read_b128; the 4 quads hit disjoint bank quartets -> no net conflict.
// Fragment layouts (mfma_f32_16x16x32_bf16, m89-verified):
//   A: m=lane&15, k=quad*8+j ; B: n=lane&15, k=quad*8+j
//   C: col=lane&15, row=quad*4+reg
// EPI: 0 = bf16 heads [n][h][t][d]; 1 = bf16 V-transposed [n][h][d][t];
//      2 = fp32 row-major [m][1024].
// ---------------------------------------------------------------------------
template <int EPI>
__global__ __launch_bounds__(256) void gemm_mfma(
    const ubf16* __restrict__ X, const ubf16* __restrict__ Wt,
    const float* __restrict__ bias, void* __restrict__ Yv)
{
    __shared__ ubf16 As[128][32];  // [m][k], 64 B rows, unpadded (DMA layout)
    __shared__ ubf16 Bs[128][32];  // [n][k]

    const int tid = threadIdx.x;
    const int mb = blockIdx.x * 128, nb = blockIdx.y * 128;
    const int w = tid >> 6, lid = tid & 63, quad = lid >> 4, l15 = lid & 15;
    const int wr = (w >> 1) * 64, wc = (w & 1) * 64;

    // DMA source pattern: lane covers row w*32 + (lid>>2), col chunk (lid&3)*8
    const int drow = w * 32 + (lid >> 2);
    const int dcol = (lid & 3) * 8;

    floatx4 acc[4][4] = {};

    for (int kb = 0; kb < 1024; kb += 32) {
        if (kb) __syncthreads();  // all frag reads of prev iter done
        {
            const ubf16* ga = X  + (size_t)(mb + drow) * 1024 + kb + dcol;
            const ubf16* gb = Wt + (size_t)(nb + drow) * 1024 + kb + dcol;
            async_copy16(ga,               &As[w * 32][0]);
            async_copy16(ga + 16 * 1024,   &As[w * 32 + 16][0]);
            async_copy16(gb,               &Bs[w * 32][0]);
            async_copy16(gb + 16 * 1024,   &Bs[w * 32 + 16][0]);
        }
        __syncthreads();  // implies vmcnt drain: DMA complete + visible

        short8 af[4], bf[4];
#pragma unroll
        for (int i = 0; i < 4; ++i)
            af[i] = *(const short8*)(&As[wr + i * 16 + l15][quad * 8]);
#pragma unroll
        for (int j = 0; j < 4; ++j)
            bf[j] = *(const short8*)(&Bs[wc + j * 16 + l15][quad * 8]);
#pragma unroll
        for (int i = 0; i < 4; ++i)
#pragma unroll
            for (int j = 0; j < 4; ++j)
                acc[i][j] = __builtin_amdgcn_mfma_f32_16x16x32_bf16(
                    af[i], bf[j], acc[i][j], 0, 0, 0);
    }

    // epilogue
#pragma unroll
    for (int j = 0; j < 4; ++j) {
        const int c = nb + wc + j * 16 + l15;
        const float bx = bias[c];
#pragma unroll
        for (int i = 0; i < 4; ++i) {
            if (EPI == 2) {
                float* Y = (float*)Yv;
#pragma unroll
                for (int r = 0; r < 4; ++r) {
                    const int m = mb + wr + i * 16 + quad * 4 + r;
                    Y[(size_t)m * DM + c] = acc[i][j][r] + bx;
                }
            } else if (EPI == 0) {
                ubf16* Y = (ubf16*)Yv;
                const int h = c >> 6, d = c & 63;
#pragma unroll
                for (int r = 0; r < 4; ++r) {
                    const int m = mb + wr + i * 16 + quad * 4 + r;
                    const int n = m >> 11, t = m & 2047;
                    Y[(((size_t)(n * HEADS + h)) * T_S + t) * DK + d] =
                        f2bf(acc[i][j][r] + bx);
                }
            } else {  // EPI 1: V transposed [n][h][d][t]
                ubf16* Y = (ubf16*)Yv;
                const int h = c >> 6, d = c & 63;
                const int m0 = mb + wr + i * 16 + quad * 4;
                const int n = m0 >> 11, t0 = m0 & 2047;
                ushort4 o;
                o.x = f2bf(acc[i][j][0] + bx);
                o.y = f2bf(acc[i][j][1] + bx);
                o.z = f2bf(acc[i][j][2] + bx);
                o.w = f2bf(acc[i][j][3] + bx);
                *(ushort4*)(Y + (((size_t)(n * HEADS + h)) * DK + d) * T_S + t0) = o;
            }
        }
    }
}

// ---------------------------------------------------------------------------
// MFMA flash attention (unchanged from round 6 — isolate the GEMM delta).
// ---------------------------------------------------------------------------
__global__ __launch_bounds__(256) void attn_mfma(
    const ubf16* __restrict__ Qh, const ubf16* __restrict__ Kh,
    const ubf16* __restrict__ Vt, const int* __restrict__ pm,
    ubf16* __restrict__ A)
{
    __shared__ ubf16 Qs[64][72];  // [q][d]
    __shared__ ubf16 Ks[64][72];  // [key][d]
    __shared__ ubf16 Vs[64][72];  // [d][key]
    __shared__ ubf16 Ps[64][72];  // [q][key], per-wave 16-row slabs
    __shared__ float lbuf[4][16];

    const int tid = threadIdx.x;
    const int w = tid >> 6, lid = tid & 63, quad = lid >> 4, l15 = lid & 15;
    const int qt = (int)gridDim.x - 1 - (int)blockIdx.x;
    const int h = blockIdx.y, n = blockIdx.z;
    const int qb = qt * 64;
    const size_t qkbase = ((size_t)(n * HEADS + h)) * T_S * DK;
    const size_t vbase  = ((size_t)(n * HEADS + h)) * DK * T_S;
    const int sr = tid >> 2, skc = (tid & 3) * 16;

    {
        const ubf16* p = Qh + qkbase + (size_t)(qb + sr) * DK + skc;
        *(uint4*)(&Qs[sr][skc])     = *(const uint4*)p;
        *(uint4*)(&Qs[sr][skc + 8]) = *(const uint4*)(p + 8);
    }
    __syncthreads();
    const short8 q0 = *(const short8*)(&Qs[w * 16 + l15][quad * 8]);
    const short8 q1 = *(const short8*)(&Qs[w * 16 + l15][32 + quad * 8]);

    floatx4 o[4] = {};   // O^T: d = db*16+quad*4+r, q = w*16+l15
    float lsum[4] = {};  // partial row sums, q = w*16+quad*4+r

    for (int kt = 0; kt <= qt; ++kt) {
        const ubf16* kp = Kh + qkbase + (size_t)(kt * 64 + sr) * DK + skc;
        const ubf16* vp = Vt + vbase + (size_t)sr * T_S + kt * 64 + skc;
        uint4 k0 = *(const uint4*)kp, k1 = *(const uint4*)(kp + 8);
        uint4 v0 = *(const uint4*)vp, v1 = *(const uint4*)(vp + 8);
        const int pmv = pm[(size_t)n * T_S + kt * 64 + lid];
        __syncthreads();  // protect previous iteration's Ks/Vs reads
        *(uint4*)(&Ks[sr][skc])     = k0;
        *(uint4*)(&Ks[sr][skc + 8]) = k1;
        *(uint4*)(&Vs[sr][skc])     = v0;
        *(uint4*)(&Vs[sr][skc + 8]) = v1;
        __syncthreads();

        // ---- S = Q K^T: 8 MFMAs.  C-layout: q=quad*4+r, key=cb*16+l15 ----
        floatx4 s[4] = {};
#pragma unroll
        for (int cb = 0; cb < 4; ++cb) {
            short8 kf0 = *(const short8*)(&Ks[cb * 16 + l15][quad * 8]);
            short8 kf1 = *(const short8*)(&Ks[cb * 16 + l15][32 + quad * 8]);
            s[cb] = __builtin_amdgcn_mfma_f32_16x16x32_bf16(q0, kf0, s[cb], 0, 0, 0);
            s[cb] = __builtin_amdgcn_mfma_f32_16x16x32_bf16(q1, kf1, s[cb], 0, 0, 0);
        }

        // ---- p = exp(s/8), masked -> 0; accumulate l; stash P ----
        const unsigned long long pmask = __ballot(pmv != 0);
        const bool diag = (kt == qt);
#pragma unroll
        for (int cb = 0; cb < 4; ++cb) {
            const unsigned okb = ((unsigned)(pmask >> (cb * 16)) >> l15) & 1u;
            const int col = cb * 16 + l15;   // in-tile key index
#pragma unroll
            for (int r = 0; r < 4; ++r) {
                float p = __expf(s[cb][r] * 0.125f);
                if (!okb || (diag && col > (w * 16 + quad * 4 + r))) p = 0.f;
                lsum[r] += p;
                Ps[w * 16 + quad * 4 + r][col] = f2bf(p);
            }
        }
        __asm__ volatile("s_waitcnt lgkmcnt(0)" ::: "memory");
        __builtin_amdgcn_wave_barrier();

        // ---- O^T += MFMA(A=V^T, B=P): 8 MFMAs ----
        short8 pf0 = *(const short8*)(&Ps[w * 16 + l15][quad * 8]);
        short8 pf1 = *(const short8*)(&Ps[w * 16 + l15][32 + quad * 8]);
#pragma unroll
        for (int db = 0; db < 4; ++db) {
            short8 vf0 = *(const short8*)(&Vs[db * 16 + l15][quad * 8]);
            short8 vf1 = *(const short8*)(&Vs[db * 16 + l15][32 + quad * 8]);
            o[db] = __builtin_amdgcn_mfma_f32_16x16x32_bf16(vf0, pf0, o[db], 0, 0, 0);
            o[db] = __builtin_amdgcn_mfma_f32_16x16x32_bf16(vf1, pf1, o[db], 0, 0, 0);
        }
    }

    // ---- final l reduction ----
#pragma unroll
    for (int r = 0; r < 4; ++r) {
        lsum[r] += __shfl_xor(lsum[r], 1);
        lsum[r] += __shfl_xor(lsum[r], 2);
        lsum[r] += __shfl_xor(lsum[r], 4);
        lsum[r] += __shfl_xor(lsum[r], 8);
    }
    if (l15 == 0) {
#pragma unroll
        for (int r = 0; r < 4; ++r) lbuf[w][quad * 4 + r] = lsum[r];
    }
    __asm__ volatile("s_waitcnt lgkmcnt(0)" ::: "memory");
    __builtin_amdgcn_wave_barrier();
    const float lq = lbuf[w][l15];
    const float inv = lq > 0.f ? 1.0f / lq : 0.f;

    ubf16* ap = A + ((size_t)n * T_S + qb + w * 16 + l15) * DM + h * DK;
#pragma unroll
    for (int db = 0; db < 4; ++db) {
        ushort4 ov;
        ov.x = f2bf(o[db][0] * inv);
        ov.y = f2bf(o[db][1] * inv);
        ov.z = f2bf(o[db][2] * inv);
        ov.w = f2bf(o[db][3] * inv);
        *(ushort4*)(ap + db * 16 + quad * 4) = ov;
    }
}

// ---------------------------------------------------------------------------
extern "C" void kernel_launch(void* const* d_in, const int* in_sizes, int n_in,
                              void* d_out, int out_size, void* d_ws, size_t ws_size,
                              hipStream_t stream)
{
    const float* q  = (const float*)d_in[0];
    const float* k  = (const float*)d_in[1];
    const float* v  = (const float*)d_in[2];
    const int*   pm = (const int*)d_in[3];
    const float* Wq = (const float*)d_in[4];
    const float* bq = (const float*)d_in[5];
    const float* Wk = (const float*)d_in[6];
    const float* bk = (const float*)d_in[7];
    const float* Wv = (const float*)d_in[8];
    const float* bv = (const float*)d_in[9];
    const float* Wo = (const float*)d_in[10];
    const float* bo = (const float*)d_in[11];
    float* out = (float*)d_out;

    const size_t WT_E = (size_t)1024 * 1024;      // per-weight bf16 elems (2 MiB)
    const size_t HB_E = (size_t)8192 * 1024;      // batched per-tensor elems (16 MiB)
    const size_t PB_E = (size_t)2048 * 1024;      // per-batch elems (4 MiB)

    ubf16* WtQ = (ubf16*)d_ws;
    ubf16* WtK = WtQ + WT_E;
    ubf16* WtV = WtK + WT_E;
    ubf16* WtO = WtV + WT_E;
    ubf16* base = WtO + WT_E;

    dim3 blk(256);
    dim3 gtr(16, 16);
    wtrans<<<gtr, blk, 0, stream>>>(Wq, WtQ);
    wtrans<<<gtr, blk, 0, stream>>>(Wk, WtK);
    wtrans<<<gtr, blk, 0, stream>>>(Wv, WtV);
    wtrans<<<gtr, blk, 0, stream>>>(Wo, WtO);

    const size_t need_batched = (4 * WT_E + 4 * HB_E) * sizeof(ubf16);  // 72 MiB
    if (ws_size >= need_batched) {
        ubf16* Qh = base;
        ubf16* Kh = Qh + HB_E;
        ubf16* Vt = Kh + HB_E;
        ubf16* Aw = Vt + HB_E;       // doubles as the bf16-convert staging buf
        dim3 gg(64, 8);              // M=8192, N=1024, 128x128 tiles
        const int n8 = (int)(HB_E / 8);
        cvt_bf16<<<n8 / 256, blk, 0, stream>>>(q, Aw, n8);
        gemm_mfma<0><<<gg, blk, 0, stream>>>(Aw, WtQ, bq, Qh);
        cvt_bf16<<<n8 / 256, blk, 0, stream>>>(k, Aw, n8);
        gemm_mfma<0><<<gg, blk, 0, stream>>>(Aw, WtK, bk, Kh);
        cvt_bf16<<<n8 / 256, blk, 0, stream>>>(v, Aw, n8);
        gemm_mfma<1><<<gg, blk, 0, stream>>>(Aw, WtV, bv, Vt);
        dim3 ga(32, HEADS, N_B);     // 2048 blocks
        attn_mfma<<<ga, blk, 0, stream>>>(Qh, Kh, Vt, pm, Aw);
        gemm_mfma<2><<<gg, blk, 0, stream>>>(Aw, WtO, bo, out);
    } else {
        // per-batch fallback (24 MiB workspace)
        ubf16* Qh = base;
        ubf16* Kh = Qh + PB_E;
        ubf16* Vt = Kh + PB_E;
        ubf16* Aw = Vt + PB_E;
        dim3 gg(16, 8);
        dim3 ga(32, HEADS, 1);
        const int n8 = (int)(PB_E / 8);
        for (int n = 0; n < N_B; ++n) {
            const size_t xoff = (size_t)n * T_S * DM;
            cvt_bf16<<<n8 / 256, blk, 0, stream>>>(q + xoff, Aw, n8);
            gemm_mfma<0><<<gg, blk, 0, stream>>>(Aw, WtQ, bq, Qh);
            cvt_bf16<<<n8 / 256, blk, 0, stream>>>(k + xoff, Aw, n8);
            gemm_mfma<0><<<gg, blk, 0, stream>>>(Aw, WtK, bk, Kh);
            cvt_bf16<<<n8 / 256, blk, 0, stream>>>(v + xoff, Aw, n8);
            gemm_mfma<1><<<gg, blk, 0, stream>>>(Aw, WtV, bv, Vt);
            attn_mfma<<<ga, blk, 0, stream>>>(Qh, Kh, Vt, pm + n * T_S, Aw);
            gemm_mfma<2><<<gg, blk, 0, stream>>>(Aw, WtO, bo, out + xoff);
        }
    }
}